// Round 5
// baseline (482.006 us; speedup 1.0000x reference)
//
#include <hip/hip_runtime.h>
#include <hip/hip_bf16.h>

#define T_SEQ 4096
#define HID   2048
#define NH    16
#define NKV   4
#define HD    128
#define QKV_N 3072
// (1/sqrt(128)) * log2(e) folded into q at rope_norm time; attention uses exp2
#define QSCALE 0.12751744f
// static softmax max (log2 units); folded into MFMA accumulator init
#define SMAX 24.0f

typedef unsigned short u16;
typedef __bf16 bf16x8 __attribute__((ext_vector_type(8)));
typedef float floatx4 __attribute__((ext_vector_type(4)));
typedef float floatx16 __attribute__((ext_vector_type(16)));

__device__ __forceinline__ float b2f(u16 u) {
  union { unsigned int i; float f; } x; x.i = ((unsigned int)u) << 16; return x.f;
}
__device__ __forceinline__ u16 f2b(float f) {
  union { float f; unsigned int i; } x; x.f = f;
  unsigned int i = x.i;
  unsigned int r = (i + 0x7FFFu + ((i >> 16) & 1u)) >> 16;
  return (u16)r;
}
__device__ __forceinline__ void gload_lds16(const u16* g, u16* lds) {
  __builtin_amdgcn_global_load_lds(
      (const __attribute__((address_space(1))) unsigned int*)g,
      (__attribute__((address_space(3))) unsigned int*)lds, 16, 0, 0);
}

// ---------------- f32 -> bf16 bulk convert ----------------
__global__ __launch_bounds__(256) void conv_f32_bf16(const float* __restrict__ src,
                                                     u16* __restrict__ dst, int n8) {
  int i = blockIdx.x * 256 + threadIdx.x;
  if (i >= n8) return;
  const float4* s = (const float4*)(src + (size_t)i * 8);
  float4 a = s[0], b = s[1];
  union { u16 h[8]; uint4 u; } r;
  r.h[0] = f2b(a.x); r.h[1] = f2b(a.y); r.h[2] = f2b(a.z); r.h[3] = f2b(a.w);
  r.h[4] = f2b(b.x); r.h[5] = f2b(b.y); r.h[6] = f2b(b.z); r.h[7] = f2b(b.w);
  *(uint4*)(dst + (size_t)i * 8) = r.u;
}

// ---------------- bf16 GEMM: C[M,N] = A[M,K]*B[N,K]^T ----------------
template <int CF>
__global__ __launch_bounds__(256) void gemm_bt(const u16* __restrict__ A, int lda,
                                               const u16* __restrict__ B, int ldb,
                                               void* __restrict__ Cv, int ldc, int K) {
  __shared__ __align__(16) u16 sA[128 * 32];
  __shared__ __align__(16) u16 sB[128 * 32];
  const int tid = threadIdx.x;
  const int wave = tid >> 6, lane = tid & 63;
  const int row0 = blockIdx.y * 128, col0 = blockIdx.x * 128;
  const int wm = (wave >> 1) * 64, wn = (wave & 1) * 64;
  const int frow = lane & 15, fk = (lane >> 4) * 8;

  floatx4 acc[4][4];
#pragma unroll
  for (int i = 0; i < 4; i++)
#pragma unroll
    for (int j = 0; j < 4; j++) acc[i][j] = (floatx4){0.f, 0.f, 0.f, 0.f};

  const int c0 = wave * 2;
  const int v0 = c0 * 64 + lane;
  const int v1 = v0 + 64;
  const u16* gA0 = A + (size_t)(row0 + (v0 >> 2)) * lda + (v0 & 3) * 8;
  const u16* gA1 = A + (size_t)(row0 + (v1 >> 2)) * lda + (v1 & 3) * 8;
  const u16* gB0 = B + (size_t)(col0 + (v0 >> 2)) * ldb + (v0 & 3) * 8;
  const u16* gB1 = B + (size_t)(col0 + (v1 >> 2)) * ldb + (v1 & 3) * 8;

  for (int k0 = 0; k0 < K; k0 += 32) {
    gload_lds16(gA0 + k0, sA + c0 * 512);
    gload_lds16(gA1 + k0, sA + c0 * 512 + 512);
    gload_lds16(gB0 + k0, sB + c0 * 512);
    gload_lds16(gB1 + k0, sB + c0 * 512 + 512);
    __syncthreads();
    bf16x8 af[4], bfv[4];
#pragma unroll
    for (int i = 0; i < 4; i++) {
      af[i]  = *(const bf16x8*)(sA + (wm + i * 16 + frow) * 32 + fk);
      bfv[i] = *(const bf16x8*)(sB + (wn + i * 16 + frow) * 32 + fk);
    }
#pragma unroll
    for (int i = 0; i < 4; i++)
#pragma unroll
      for (int j = 0; j < 4; j++)
        acc[i][j] = __builtin_amdgcn_mfma_f32_16x16x32_bf16(af[i], bfv[j], acc[i][j], 0, 0, 0);
    __syncthreads();
  }
  const int crow = (lane >> 4) * 4, ccol = lane & 15;
#pragma unroll
  for (int i = 0; i < 4; i++)
#pragma unroll
    for (int j = 0; j < 4; j++)
#pragma unroll
      for (int r = 0; r < 4; r++) {
        int rr = row0 + wm + i * 16 + crow + r;
        int cc = col0 + wn + j * 16 + ccol;
        if (CF) ((float*)Cv)[(size_t)rr * ldc + cc] = acc[i][j][r];
        else    ((u16*)Cv)[(size_t)rr * ldc + cc] = f2b(acc[i][j][r]);
      }
}

// ---------------- RoPE + RMSNorm (q scaled by QSCALE) ----------------
// fast hw sincos: angle -> revolutions -> fract -> v_sin/v_cos.
__device__ __forceinline__ void fast_sincos(float ang, float* s, float* c) {
  float r = ang * 0.15915494309189535f;
  r -= floorf(r);
  *s = __builtin_amdgcn_sinf(r);
  *c = __builtin_amdgcn_cosf(r);
}

__global__ __launch_bounds__(256) void rope_norm(const int* __restrict__ pos_arr,
                                                 u16* __restrict__ qkv,
                                                 const float* __restrict__ qnw,
                                                 const float* __restrict__ knw) {
  const int t = blockIdx.x;
  const int tid = threadIdx.x;
  const int lane = tid & 63, wave = tid >> 6;
  u16* row = qkv + (size_t)t * QKV_N;
  const float pos = (float)pos_arr[t];

  float qv[8];
  float ssq = 0.f;
#pragma unroll
  for (int i = 0; i < 8; i++) {
    int e = tid * 8 + i;
    int r = e & 127, ih = e & 63;
    float invf = exp2f(-(float)ih * 0.20762050593046015f); // log2(10000)/64
    float ang = pos * invf;
    float s, c;
    fast_sincos(ang, &s, &c);
    float val;
    if (r < 64) val = b2f(row[e]) * c - b2f(row[e + 64]) * s;
    else        val = b2f(row[e]) * c + b2f(row[e - 64]) * s;
    qv[i] = val;
    ssq += val * val;
  }
  float kv[2];
  float ssk = 0.f;
  const u16* krow = row + HID;
#pragma unroll
  for (int i = 0; i < 2; i++) {
    int e = tid * 2 + i;
    int r = e & 127, ih = e & 63;
    float invf = exp2f(-(float)ih * 0.20762050593046015f);
    float ang = pos * invf;
    float s, c;
    fast_sincos(ang, &s, &c);
    float val;
    if (r < 64) val = b2f(krow[e]) * c - b2f(krow[e + 64]) * s;
    else        val = b2f(krow[e]) * c + b2f(krow[e - 64]) * s;
    kv[i] = val;
    ssk += val * val;
  }
#pragma unroll
  for (int off = 1; off < 64; off <<= 1) {
    ssq += __shfl_xor(ssq, off);
    ssk += __shfl_xor(ssk, off);
  }
  __shared__ float rq[4], rk[4];
  if (lane == 0) { rq[wave] = ssq; rk[wave] = ssk; }
  __syncthreads();  // also orders all in-place reads before writes below
  float sq = rq[0] + rq[1] + rq[2] + rq[3];
  float sk = rk[0] + rk[1] + rk[2] + rk[3];
  float qsc = rsqrtf(sq * (1.0f / 2048.0f) + 1e-5f) * QSCALE;
  float ksc = rsqrtf(sk * (1.0f / 512.0f) + 1e-5f);
#pragma unroll
  for (int i = 0; i < 8; i++) {
    int e = tid * 8 + i;
    row[e] = f2b(qv[i] * qsc * qnw[e]);
  }
#pragma unroll
  for (int i = 0; i < 2; i++) {
    int e = tid * 2 + i;
    row[HID + e] = f2b(kv[i] * ksc * knw[e]);
  }
}

// ---------------- V transpose: vt[kvh][d][t] ----------------
__global__ __launch_bounds__(256) void transpose_v(const u16* __restrict__ qkv,
                                                   u16* __restrict__ vt) {
  __shared__ __align__(16) u16 tile[64][136];
  const int tid = threadIdx.x;
  const int h = blockIdx.y;
  const int t0 = blockIdx.x * 64;
#pragma unroll
  for (int p = 0; p < 4; p++) {
    int v = p * 256 + tid;
    int r = v >> 4, c = v & 15;
    const u16* g = qkv + (size_t)(t0 + r) * QKV_N + (HID + NKV * HD) + h * HD + c * 8;
    *(uint4*)(&tile[r][c * 8]) = *(const uint4*)g;
  }
  __syncthreads();
#pragma unroll
  for (int p = 0; p < 4; p++) {
    int v = p * 256 + tid;
    int d = v >> 3, c8 = v & 7;
    union { u16 s[8]; uint4 q; } tmp;
#pragma unroll
    for (int i = 0; i < 8; i++) tmp.s[i] = tile[c8 * 8 + i][d];
    u16* g = vt + ((size_t)h * HD + d) * T_SEQ + t0 + c8 * 8;
    *(uint4*)g = tmp.q;
  }
}

// ---------------- Flash attention v7 ----------------
// v6 + occupancy fix: V is L2-resident (each XCD touches one kvh: K 1MB +
// V 1MB < 4MB L2), and the staged sV tile had only 4x reuse -> drop V LDS
// staging entirely; PV reads V-fragments directly from vt (16B/lane, 32
// cache lines/wave). LDS 64KB -> 32KB so all 3 blocks/CU of the schedule
// are co-resident (12 waves/CU vs 8). K staging pointers are incremental
// (no per-step 64-bit mul chains).
__global__ __launch_bounds__(256, 3) void attn_kernel(u16* __restrict__ qkv,
                                                      const u16* __restrict__ vt,
                                                      float* __restrict__ scratch,
                                                      float* __restrict__ lbuf) {
  __shared__ __align__(16) u16 sK[2][64 * 128];  // [kv][d-chunk swizzled], 2x16KB
  const int tid = threadIdx.x;
  const int wave = tid >> 6, lane = tid & 63;
  const int bid = blockIdx.x;

  // schedule: per-XCD (x = bid&7) list, longest-first.
  // slots 0..79: 8 band-pairs of 10 = {even band s: 4 split parts (qt=s-1)
  // + 2 unsplit (qt=s/2-1)} then {odd band s-1: 4 split parts (qt=s-2)}.
  // slots 80..95: unsplit qt 7..0.
  const int x = bid & 7, slot = bid >> 3;
  int h, qt, part = 0;
  bool split;
  if (slot < 80) {
    const int pr = slot / 10, r = slot - pr * 10;
    if (r < 4)      { qt = 31 - 2 * pr; part = r & 1;       h = 2 * x + (r >> 1);       split = true;  }
    else if (r < 6) { qt = 15 - pr;                         h = 2 * x + (r - 4);        split = false; }
    else            { qt = 30 - 2 * pr; part = (r - 6) & 1; h = 2 * x + ((r - 6) >> 1); split = true;  }
  } else {
    const int j = slot - 80;
    qt = 7 - (j >> 1);
    h = 2 * x + (j & 1);
    split = false;
  }
  const int s_begin = (split && part) ? (qt + 1) : 0;
  const int s_end   = split ? (part ? 2 * (qt + 1) : (qt + 1)) : 2 * (qt + 1);

  const int kvh = h >> 2;
  const int ql = lane & 31;
  const int fq2 = lane >> 5;
  const u16* kbase = qkv + HID + (size_t)kvh * HD;
  const u16* vbase = vt + (size_t)kvh * HD * T_SEQ;

  const int qw = qt * 128 + wave * 32;
  const int qmax = qw + 31;
  const int qrow = qw + ql;
  // Q B-fragments (8 k-chunks of 16 d)
  bf16x8 qf[8];
  const u16* qp = qkv + (size_t)qrow * QKV_N + h * HD + fq2 * 8;
#pragma unroll
  for (int kc = 0; kc < 8; kc++) qf[kc] = *(const bf16x8*)(qp + kc * 16);
  // V row pointers for direct-from-L2 PV fragment reads
  const u16* vrow[4];
#pragma unroll
  for (int dt = 0; dt < 4; dt++) vrow[dt] = vbase + (size_t)(dt * 32 + ql) * T_SEQ;

  floatx16 O[4];
#pragma unroll
  for (int dt = 0; dt < 4; dt++)
#pragma unroll
    for (int r = 0; r < 16; r++) O[dt][r] = 0.f;
  float l_part = 0.f;

  // incremental per-thread K staging source pointers (4 chunks)
  const u16* gk[4];
#pragma unroll
  for (int i = 0; i < 4; i++) {
    int c = wave * 256 + i * 64 + lane;
    int kv = c >> 4, ch = c & 15;
    gk[i] = kbase + (size_t)(s_begin * 64 + kv) * QKV_N + ((ch ^ (kv & 7)) * 8);
  }

  const int nsteps = s_end - s_begin;
  // stage first K tile into buf0
#pragma unroll
  for (int i = 0; i < 4; i++) {
    gload_lds16(gk[i], sK[0] + (wave * 256 + i * 64) * 8);
    gk[i] += 64 * QKV_N;
  }
#pragma unroll 1
  for (int st = 0; st < nsteps; st++) {
    const int s = s_begin + st;
    __syncthreads();  // staged buf[st&1] visible; prefetch from st-1 drained
    if (st + 1 < nsteps) {
#pragma unroll
      for (int i = 0; i < 4; i++) {
        gload_lds16(gk[i], sK[(st + 1) & 1] + (wave * 256 + i * 64) * 8);
        gk[i] += 64 * QKV_N;
      }
    }
    const int kv0 = s * 64;
    if (kv0 <= qmax) {
      const u16* sk = sK[st & 1];
      const int ntv = (kv0 + 32 <= qmax) ? 2 : 1;
#pragma unroll
      for (int nt = 0; nt < 2; nt++) {
        if (nt < ntv) {
          floatx16 S;
#pragma unroll
          for (int r = 0; r < 16; r++) S[r] = -SMAX;
          __builtin_amdgcn_s_setprio(1);
#pragma unroll
          for (int kc = 0; kc < 8; kc++) {
            int ch = (kc * 2 + fq2) ^ (ql & 7);
            bf16x8 kf = *(const bf16x8*)(sk + ((nt * 32 + ql) * 16 + ch) * 8);
            S = __builtin_amdgcn_mfma_f32_32x32x16_bf16(kf, qf[kc], S, 0, 0, 0);
          }
          __builtin_amdgcn_s_setprio(0);
          const bool tmask = (kv0 + nt * 32 + 31) > qw;
#pragma unroll
          for (int r = 0; r < 16; r++) {
            float v = S[r];
            if (tmask) {
              int kvg = kv0 + nt * 32 + (r & 3) + ((r >> 2) << 3) + (fq2 << 2);
              v = (kvg > qrow) ? -1e30f : v;
            }
            float p = __builtin_amdgcn_exp2f(v);
            l_part += p;
            S[r] = p;
          }
          // In-register P (T12): pack f32 pairs to bf16 words, then
          // permlane32_swap(lo-group, hi-group) -> {j0/1 word, j4/5 word}.
          unsigned cp[8];
#pragma unroll
          for (int i = 0; i < 8; i++) {
            unsigned wv;
            asm("v_cvt_pk_bf16_f32 %0, %1, %2"
                : "=v"(wv) : "v"(S[i * 2]), "v"(S[i * 2 + 1]));
            cp[i] = wv;
          }
          union { unsigned u[4]; bf16x8 v; } pf0, pf1;
          {
            auto r0 = __builtin_amdgcn_permlane32_swap(cp[0], cp[2], false, false);
            pf0.u[0] = r0[0]; pf0.u[2] = r0[1];
            auto r1 = __builtin_amdgcn_permlane32_swap(cp[1], cp[3], false, false);
            pf0.u[1] = r1[0]; pf0.u[3] = r1[1];
            auto r2 = __builtin_amdgcn_permlane32_swap(cp[4], cp[6], false, false);
            pf1.u[0] = r2[0]; pf1.u[2] = r2[1];
            auto r3 = __builtin_amdgcn_permlane32_swap(cp[5], cp[7], false, false);
            pf1.u[1] = r3[0]; pf1.u[3] = r3[1];
          }
          __builtin_amdgcn_s_setprio(1);
#pragma unroll
          for (int c = 0; c < 2; c++) {
            bf16x8 pf = c ? pf1.v : pf0.v;
#pragma unroll
            for (int dt = 0; dt < 4; dt++) {
              // direct L2 read of V fragment (unswizzled vt address)
              const u16* vp = vrow[dt] + kv0 + ((nt * 2 + c) * 2 + fq2) * 8;
              bf16x8 vf = *(const bf16x8*)vp;
              O[dt] = __builtin_amdgcn_mfma_f32_32x32x16_bf16(vf, pf, O[dt], 0, 0, 0);
            }
          }
          __builtin_amdgcn_s_setprio(0);
        }
      }
    }
  }
  float l = l_part + __shfl_xor(l_part, 32);
  if (!split) {
    float inv = 1.0f / fmaxf(l, 1e-30f);
    u16* orow = qkv + (size_t)qrow * QKV_N + h * HD;
#pragma unroll
    for (int dt = 0; dt < 4; dt++)
#pragma unroll
      for (int rg = 0; rg < 4; rg++) {
        union { u16 hh[4]; uint2 uu; } wv;
#pragma unroll
        for (int rr = 0; rr < 4; rr++) wv.hh[rr] = f2b(O[dt][rg * 4 + rr] * inv);
        *(uint2*)(orow + dt * 32 + rg * 8 + fq2 * 4) = wv.uu;
      }
  } else {
    // plain stores into this part's private region; no atomics, no memset.
    const int tile = h * 16 + (qt - 16);
    float* obase = scratch + (size_t)(part * 256 + tile) * 16384 +
                   (size_t)(wave * 32 + ql) * 128;
#pragma unroll
    for (int dt = 0; dt < 4; dt++)
#pragma unroll
      for (int rg = 0; rg < 4; rg++) {
        float4 wv = {O[dt][rg * 4 + 0], O[dt][rg * 4 + 1],
                     O[dt][rg * 4 + 2], O[dt][rg * 4 + 3]};
        *(float4*)(obase + dt * 32 + rg * 8 + fq2 * 4) = wv;
      }
    if (fq2 == 0) lbuf[(part * 256 + tile) * 128 + wave * 32 + ql] = l;
  }
}

// ---------------- combine split-tile partials ----------------
__global__ __launch_bounds__(256) void combine_split(const float* __restrict__ scratch,
                                                     const float* __restrict__ lbuf,
                                                     u16* __restrict__ qkv) {
  const int t = blockIdx.x;              // tile: h*16 + (qt-16)
  const int h = t >> 4, qt = 16 + (t & 15);
  const int tid = threadIdx.x;
  const int rsub = tid >> 4;             // 0..15
  const int d0 = (tid & 15) * 8;
  const float* s0 = scratch + (size_t)t * 16384;
  const float* s1 = scratch + (size_t)(256 + t) * 16384;
#pragma unroll
  for (int p = 0; p < 8; p++) {
    int r = p * 16 + rsub;
    float l0 = lbuf[t * 128 + r];
    float l1 = lbuf[32768 + t * 128 + r];
    float inv = 1.0f / fmaxf(l0 + l1, 1e-30f);
    const float4* a4 = (const float4*)(s0 + (size_t)r * 128 + d0);
    const float4* b4 = (const float4*)(s1 + (size_t)r * 128 + d0);
    float4 a0 = a4[0], a1 = a4[1];
    float4 b0 = b4[0], b1 = b4[1];
    union { u16 hh[8]; uint4 u; } wv;
    wv.hh[0] = f2b((a0.x + b0.x) * inv); wv.hh[1] = f2b((a0.y + b0.y) * inv);
    wv.hh[2] = f2b((a0.z + b0.z) * inv); wv.hh[3] = f2b((a0.w + b0.w) * inv);
    wv.hh[4] = f2b((a1.x + b1.x) * inv); wv.hh[5] = f2b((a1.y + b1.y) * inv);
    wv.hh[6] = f2b((a1.z + b1.z) * inv); wv.hh[7] = f2b((a1.w + b1.w) * inv);
    *(uint4*)(qkv + (size_t)(qt * 128 + r) * QKV_N + h * HD + d0) = wv.u;
  }
}

extern "C" void kernel_launch(void* const* d_in, const int* in_sizes, int n_in,
                              void* d_out, int out_size, void* d_ws, size_t ws_size,
                              hipStream_t stream) {
  const int* positions = (const int*)d_in[0];
  const float* hidden = (const float*)d_in[1];
  const float* w_qkv = (const float*)d_in[2];
  const float* w_o = (const float*)d_in[3];
  const float* qnw = (const float*)d_in[4];
  const float* knw = (const float*)d_in[5];
  float* out = (float*)d_out;

  u16* qkv  = (u16*)d_ws;                       // [4096][3072] bf16, 25.2 MB
  u16* bufA = qkv + (size_t)T_SEQ * QKV_N;      // hidden_bf16 (16.8 MB) -> w_o_bf16
  u16* bufB = bufA + (size_t)T_SEQ * HID;       // w_qkv_bf16 (12.6 MB) -> vt (4.2 MB)
  // l partials live in bufB's tail (free once gemm#1 consumed w_qkv_bf16):
  // vt occupies u16[0 .. 2097152); lbuf gets 2*128 KB after it.
  float* lbuf = (float*)(bufB + 2097152);
  // O partials for split tiles: d_out is dead until the final GEMM.
  // part0 at [0, 256*16384), part1 at [256*16384, 512*16384) — exactly out_size.
  float* scratch = out;

  // 0) one-shot f32 -> bf16 converts (lifetimes allow buffer reuse)
  conv_f32_bf16<<<4096, 256, 0, stream>>>(hidden, bufA, T_SEQ * HID / 8);
  conv_f32_bf16<<<3072, 256, 0, stream>>>(w_qkv, bufB, QKV_N * HID / 8);
  // 1) qkv = hidden @ w_qkv^T (bf16 out)
  gemm_bt<0><<<dim3(QKV_N / 128, T_SEQ / 128), 256, 0, stream>>>(
      bufA, HID, bufB, HID, qkv, QKV_N, HID);
  // 2) RoPE + RMSNorm in place (q pre-scaled by 1/sqrt(D)*log2e)
  rope_norm<<<T_SEQ, 256, 0, stream>>>(positions, qkv, qnw, knw);
  // 3) w_o convert (overwrites hidden_bf16) + v^T (overwrites w_qkv_bf16)
  conv_f32_bf16<<<2048, 256, 0, stream>>>(w_o, bufA, HID * HID / 8);
  transpose_v<<<dim3(T_SEQ / 64, NKV), 256, 0, stream>>>(qkv, bufB);
  // 4) flash attention, KV-split balanced schedule (no memset needed:
  //    every scratch/lbuf slot is written exactly once by its owner block)
  attn_kernel<<<768, 256, 0, stream>>>(qkv, bufB, scratch, lbuf);
  combine_split<<<256, 256, 0, stream>>>(scratch, lbuf, qkv);
  // 5) out = attn @ w_o^T (f32 out)
  gemm_bt<1><<<dim3(HID / 128, T_SEQ / 128), 256, 0, stream>>>(
      qkv, QKV_N, bufA, HID, out, HID, HID);
}

// Round 6
// 417.056 us; speedup vs baseline: 1.1557x; 1.1557x over previous
//
#include <hip/hip_runtime.h>
#include <hip/hip_bf16.h>

#define T_SEQ 4096
#define HID   2048
#define NH    16
#define NKV   4
#define HD    128
#define QKV_N 3072
// (1/sqrt(128)) * log2(e) folded into q at rope_norm time; attention uses exp2
#define QSCALE 0.12751744f
// static softmax max (log2 units); folded into MFMA accumulator init
#define SMAX 24.0f

typedef unsigned short u16;
typedef __bf16 bf16x8 __attribute__((ext_vector_type(8)));
typedef float floatx4 __attribute__((ext_vector_type(4)));
typedef float floatx16 __attribute__((ext_vector_type(16)));

__device__ __forceinline__ float b2f(u16 u) {
  union { unsigned int i; float f; } x; x.i = ((unsigned int)u) << 16; return x.f;
}
__device__ __forceinline__ u16 f2b(float f) {
  union { float f; unsigned int i; } x; x.f = f;
  unsigned int i = x.i;
  unsigned int r = (i + 0x7FFFu + ((i >> 16) & 1u)) >> 16;
  return (u16)r;
}
__device__ __forceinline__ void gload_lds16(const u16* g, u16* lds) {
  __builtin_amdgcn_global_load_lds(
      (const __attribute__((address_space(1))) unsigned int*)g,
      (__attribute__((address_space(3))) unsigned int*)lds, 16, 0, 0);
}

// ---------------- f32 -> bf16 bulk convert ----------------
__global__ __launch_bounds__(256) void conv_f32_bf16(const float* __restrict__ src,
                                                     u16* __restrict__ dst, int n8) {
  int i = blockIdx.x * 256 + threadIdx.x;
  if (i >= n8) return;
  const float4* s = (const float4*)(src + (size_t)i * 8);
  float4 a = s[0], b = s[1];
  union { u16 h[8]; uint4 u; } r;
  r.h[0] = f2b(a.x); r.h[1] = f2b(a.y); r.h[2] = f2b(a.z); r.h[3] = f2b(a.w);
  r.h[4] = f2b(b.x); r.h[5] = f2b(b.y); r.h[6] = f2b(b.z); r.h[7] = f2b(b.w);
  *(uint4*)(dst + (size_t)i * 8) = r.u;
}

// ---------------- bf16 GEMM: C[M,N] = A[M,K]*B[N,K]^T ----------------
template <int CF>
__global__ __launch_bounds__(256) void gemm_bt(const u16* __restrict__ A, int lda,
                                               const u16* __restrict__ B, int ldb,
                                               void* __restrict__ Cv, int ldc, int K) {
  __shared__ __align__(16) u16 sA[128 * 32];
  __shared__ __align__(16) u16 sB[128 * 32];
  const int tid = threadIdx.x;
  const int wave = tid >> 6, lane = tid & 63;
  const int row0 = blockIdx.y * 128, col0 = blockIdx.x * 128;
  const int wm = (wave >> 1) * 64, wn = (wave & 1) * 64;
  const int frow = lane & 15, fk = (lane >> 4) * 8;

  floatx4 acc[4][4];
#pragma unroll
  for (int i = 0; i < 4; i++)
#pragma unroll
    for (int j = 0; j < 4; j++) acc[i][j] = (floatx4){0.f, 0.f, 0.f, 0.f};

  const int c0 = wave * 2;
  const int v0 = c0 * 64 + lane;
  const int v1 = v0 + 64;
  const u16* gA0 = A + (size_t)(row0 + (v0 >> 2)) * lda + (v0 & 3) * 8;
  const u16* gA1 = A + (size_t)(row0 + (v1 >> 2)) * lda + (v1 & 3) * 8;
  const u16* gB0 = B + (size_t)(col0 + (v0 >> 2)) * ldb + (v0 & 3) * 8;
  const u16* gB1 = B + (size_t)(col0 + (v1 >> 2)) * ldb + (v1 & 3) * 8;

  for (int k0 = 0; k0 < K; k0 += 32) {
    gload_lds16(gA0 + k0, sA + c0 * 512);
    gload_lds16(gA1 + k0, sA + c0 * 512 + 512);
    gload_lds16(gB0 + k0, sB + c0 * 512);
    gload_lds16(gB1 + k0, sB + c0 * 512 + 512);
    __syncthreads();
    bf16x8 af[4], bfv[4];
#pragma unroll
    for (int i = 0; i < 4; i++) {
      af[i]  = *(const bf16x8*)(sA + (wm + i * 16 + frow) * 32 + fk);
      bfv[i] = *(const bf16x8*)(sB + (wn + i * 16 + frow) * 32 + fk);
    }
#pragma unroll
    for (int i = 0; i < 4; i++)
#pragma unroll
      for (int j = 0; j < 4; j++)
        acc[i][j] = __builtin_amdgcn_mfma_f32_16x16x32_bf16(af[i], bfv[j], acc[i][j], 0, 0, 0);
    __syncthreads();
  }
  const int crow = (lane >> 4) * 4, ccol = lane & 15;
#pragma unroll
  for (int i = 0; i < 4; i++)
#pragma unroll
    for (int j = 0; j < 4; j++)
#pragma unroll
      for (int r = 0; r < 4; r++) {
        int rr = row0 + wm + i * 16 + crow + r;
        int cc = col0 + wn + j * 16 + ccol;
        if (CF) ((float*)Cv)[(size_t)rr * ldc + cc] = acc[i][j][r];
        else    ((u16*)Cv)[(size_t)rr * ldc + cc] = f2b(acc[i][j][r]);
      }
}

// ---------------- RoPE + RMSNorm (q scaled by QSCALE) ----------------
// fast hw sincos: angle -> revolutions -> fract -> v_sin/v_cos.
__device__ __forceinline__ void fast_sincos(float ang, float* s, float* c) {
  float r = ang * 0.15915494309189535f;
  r -= floorf(r);
  *s = __builtin_amdgcn_sinf(r);
  *c = __builtin_amdgcn_cosf(r);
}

__global__ __launch_bounds__(256) void rope_norm(const int* __restrict__ pos_arr,
                                                 u16* __restrict__ qkv,
                                                 const float* __restrict__ qnw,
                                                 const float* __restrict__ knw) {
  const int t = blockIdx.x;
  const int tid = threadIdx.x;
  const int lane = tid & 63, wave = tid >> 6;
  u16* row = qkv + (size_t)t * QKV_N;
  const float pos = (float)pos_arr[t];

  float qv[8];
  float ssq = 0.f;
#pragma unroll
  for (int i = 0; i < 8; i++) {
    int e = tid * 8 + i;
    int r = e & 127, ih = e & 63;
    float invf = exp2f(-(float)ih * 0.20762050593046015f); // log2(10000)/64
    float ang = pos * invf;
    float s, c;
    fast_sincos(ang, &s, &c);
    float val;
    if (r < 64) val = b2f(row[e]) * c - b2f(row[e + 64]) * s;
    else        val = b2f(row[e]) * c + b2f(row[e - 64]) * s;
    qv[i] = val;
    ssq += val * val;
  }
  float kv[2];
  float ssk = 0.f;
  const u16* krow = row + HID;
#pragma unroll
  for (int i = 0; i < 2; i++) {
    int e = tid * 2 + i;
    int r = e & 127, ih = e & 63;
    float invf = exp2f(-(float)ih * 0.20762050593046015f);
    float ang = pos * invf;
    float s, c;
    fast_sincos(ang, &s, &c);
    float val;
    if (r < 64) val = b2f(krow[e]) * c - b2f(krow[e + 64]) * s;
    else        val = b2f(krow[e]) * c + b2f(krow[e - 64]) * s;
    kv[i] = val;
    ssk += val * val;
  }
#pragma unroll
  for (int off = 1; off < 64; off <<= 1) {
    ssq += __shfl_xor(ssq, off);
    ssk += __shfl_xor(ssk, off);
  }
  __shared__ float rq[4], rk[4];
  if (lane == 0) { rq[wave] = ssq; rk[wave] = ssk; }
  __syncthreads();  // also orders all in-place reads before writes below
  float sq = rq[0] + rq[1] + rq[2] + rq[3];
  float sk = rk[0] + rk[1] + rk[2] + rk[3];
  float qsc = rsqrtf(sq * (1.0f / 2048.0f) + 1e-5f) * QSCALE;
  float ksc = rsqrtf(sk * (1.0f / 512.0f) + 1e-5f);
#pragma unroll
  for (int i = 0; i < 8; i++) {
    int e = tid * 8 + i;
    row[e] = f2b(qv[i] * qsc * qnw[e]);
  }
#pragma unroll
  for (int i = 0; i < 2; i++) {
    int e = tid * 2 + i;
    row[HID + e] = f2b(kv[i] * ksc * knw[e]);
  }
}

// ---------------- V transpose: vt[kvh][d][t] ----------------
__global__ __launch_bounds__(256) void transpose_v(const u16* __restrict__ qkv,
                                                   u16* __restrict__ vt) {
  __shared__ __align__(16) u16 tile[64][136];
  const int tid = threadIdx.x;
  const int h = blockIdx.y;
  const int t0 = blockIdx.x * 64;
#pragma unroll
  for (int p = 0; p < 4; p++) {
    int v = p * 256 + tid;
    int r = v >> 4, c = v & 15;
    const u16* g = qkv + (size_t)(t0 + r) * QKV_N + (HID + NKV * HD) + h * HD + c * 8;
    *(uint4*)(&tile[r][c * 8]) = *(const uint4*)g;
  }
  __syncthreads();
#pragma unroll
  for (int p = 0; p < 4; p++) {
    int v = p * 256 + tid;
    int d = v >> 3, c8 = v & 7;
    union { u16 s[8]; uint4 q; } tmp;
#pragma unroll
    for (int i = 0; i < 8; i++) tmp.s[i] = tile[c8 * 8 + i][d];
    u16* g = vt + ((size_t)h * HD + d) * T_SEQ + t0 + c8 * 8;
    *(uint4*)g = tmp.q;
  }
}

// ---------------- Flash attention v8 ----------------
// R5 post-mortem: direct-V global loads coupled PV to the in-order vmcnt
// queue (every PV wait drained the K HBM prefetch) -> 2x regression.
// v8: V back in LDS (lgkm domain, decoupled) but SINGLE-buffered: K dbuf
// 32KB + V 16KB = 48KB -> 3 blocks/CU residency (the schedule offers 3).
// Per step: top syncthreads -> issue V[s] stage -> issue K[s+1] prefetch ->
// QK^T+softmax+pack for BOTH nt (covers V latency) -> vmcnt(4) (waits only
// the older V loads; K prefetch stays in flight across the raw barrier) ->
// s_barrier -> PV from sV. Mid-step barrier is uniform (outside act guard).
__global__ __launch_bounds__(256, 3) void attn_kernel(u16* __restrict__ qkv,
                                                      const u16* __restrict__ vt,
                                                      float* __restrict__ scratch,
                                                      float* __restrict__ lbuf) {
  __shared__ __align__(16) u16 sK[2][64 * 128];  // [kv][d-chunk swizzled], 2x16KB
  __shared__ __align__(16) u16 sV[128 * 64];     // [d][kv-chunk swizzled], 16KB
  const int tid = threadIdx.x;
  const int wave = tid >> 6, lane = tid & 63;
  const int bid = blockIdx.x;

  // schedule: per-XCD (x = bid&7) list, longest-first.
  const int x = bid & 7, slot = bid >> 3;
  int h, qt, part = 0;
  bool split;
  if (slot < 80) {
    const int pr = slot / 10, r = slot - pr * 10;
    if (r < 4)      { qt = 31 - 2 * pr; part = r & 1;       h = 2 * x + (r >> 1);       split = true;  }
    else if (r < 6) { qt = 15 - pr;                         h = 2 * x + (r - 4);        split = false; }
    else            { qt = 30 - 2 * pr; part = (r - 6) & 1; h = 2 * x + ((r - 6) >> 1); split = true;  }
  } else {
    const int j = slot - 80;
    qt = 7 - (j >> 1);
    h = 2 * x + (j & 1);
    split = false;
  }
  const int s_begin = (split && part) ? (qt + 1) : 0;
  const int s_end   = split ? (part ? 2 * (qt + 1) : (qt + 1)) : 2 * (qt + 1);

  const int kvh = h >> 2;
  const int ql = lane & 31;
  const int fq2 = lane >> 5;
  const u16* kbase = qkv + HID + (size_t)kvh * HD;
  const u16* vbase = vt + (size_t)kvh * HD * T_SEQ;

  const int qw = qt * 128 + wave * 32;
  const int qmax = qw + 31;
  const int qrow = qw + ql;
  // Q B-fragments (8 k-chunks of 16 d)
  bf16x8 qf[8];
  const u16* qp = qkv + (size_t)qrow * QKV_N + h * HD + fq2 * 8;
#pragma unroll
  for (int kc = 0; kc < 8; kc++) qf[kc] = *(const bf16x8*)(qp + kc * 16);
  floatx16 O[4];
#pragma unroll
  for (int dt = 0; dt < 4; dt++)
#pragma unroll
    for (int r = 0; r < 16; r++) O[dt][r] = 0.f;
  float l_part = 0.f;

  // incremental per-thread staging source pointers (4 chunks each)
  const u16* gk[4];
  const u16* gv[4];
#pragma unroll
  for (int i = 0; i < 4; i++) {
    int c = wave * 256 + i * 64 + lane;
    int kv = c >> 4, ch = c & 15;
    gk[i] = kbase + (size_t)(s_begin * 64 + kv) * QKV_N + ((ch ^ (kv & 7)) * 8);
    int d = c >> 3, c2 = c & 7;
    gv[i] = vbase + (size_t)d * T_SEQ + s_begin * 64 + ((c2 ^ (d & 7)) * 8);
  }

  const int nsteps = s_end - s_begin;
  // prologue: stage K[s_begin] into buf0
#pragma unroll
  for (int i = 0; i < 4; i++) {
    gload_lds16(gk[i], sK[0] + (wave * 256 + i * 64) * 8);
    gk[i] += 64 * QKV_N;
  }
#pragma unroll 1
  for (int st = 0; st < nsteps; st++) {
    const int s = s_begin + st;
    __syncthreads();  // K[st] visible; sV reads of st-1 drained; K prefetch drained
    // 1) issue V[s] stage FIRST (these are the 4 older vmem ops we'll count)
#pragma unroll
    for (int i = 0; i < 4; i++) {
      gload_lds16(gv[i], sV + (size_t)(wave * 256 + i * 64) * 8);
      gv[i] += 64;
    }
    // 2) issue K[s+1] prefetch (stays in flight across the mid-step barrier)
    if (st + 1 < nsteps) {
#pragma unroll
      for (int i = 0; i < 4; i++) {
        gload_lds16(gk[i], sK[(st + 1) & 1] + (wave * 256 + i * 64) * 8);
        gk[i] += 64 * QKV_N;
      }
    }
    const int kv0 = s * 64;
    const bool act = kv0 <= qmax;
    const int ntv = (kv0 + 32 <= qmax) ? 2 : 1;
    union PW { unsigned u[4]; bf16x8 v; };
    PW pA0, pA1, pB0, pB1;
    const u16* sk = sK[st & 1];
    auto qkt = [&](int nt, PW& o0, PW& o1) {
      floatx16 S;
#pragma unroll
      for (int r = 0; r < 16; r++) S[r] = -SMAX;
      __builtin_amdgcn_s_setprio(1);
#pragma unroll
      for (int kc = 0; kc < 8; kc++) {
        int ch = (kc * 2 + fq2) ^ (ql & 7);
        bf16x8 kf = *(const bf16x8*)(sk + ((nt * 32 + ql) * 16 + ch) * 8);
        S = __builtin_amdgcn_mfma_f32_32x32x16_bf16(kf, qf[kc], S, 0, 0, 0);
      }
      __builtin_amdgcn_s_setprio(0);
      const bool tmask = (kv0 + nt * 32 + 31) > qw;
#pragma unroll
      for (int r = 0; r < 16; r++) {
        float v = S[r];
        if (tmask) {
          int kvg = kv0 + nt * 32 + (r & 3) + ((r >> 2) << 3) + (fq2 << 2);
          v = (kvg > qrow) ? -1e30f : v;
        }
        float p = __builtin_amdgcn_exp2f(v);
        l_part += p;
        S[r] = p;
      }
      // In-register P (T12): cvt_pk pairs -> permlane32_swap halves.
      unsigned cp[8];
#pragma unroll
      for (int i = 0; i < 8; i++) {
        unsigned wv;
        asm("v_cvt_pk_bf16_f32 %0, %1, %2"
            : "=v"(wv) : "v"(S[i * 2]), "v"(S[i * 2 + 1]));
        cp[i] = wv;
      }
      {
        auto r0 = __builtin_amdgcn_permlane32_swap(cp[0], cp[2], false, false);
        o0.u[0] = r0[0]; o0.u[2] = r0[1];
        auto r1 = __builtin_amdgcn_permlane32_swap(cp[1], cp[3], false, false);
        o0.u[1] = r1[0]; o0.u[3] = r1[1];
        auto r2 = __builtin_amdgcn_permlane32_swap(cp[4], cp[6], false, false);
        o1.u[0] = r2[0]; o1.u[2] = r2[1];
        auto r3 = __builtin_amdgcn_permlane32_swap(cp[5], cp[7], false, false);
        o1.u[1] = r3[0]; o1.u[3] = r3[1];
      }
    };
    if (act) {
      qkt(0, pA0, pA1);
      if (ntv > 1) qkt(1, pB0, pB1);
    }
    // V[s] ready per-wave (leave the 4 younger K-prefetch loads in flight),
    // then block-wide visibility via raw barrier (no full vmcnt drain).
    if (st + 1 < nsteps) {
      asm volatile("s_waitcnt vmcnt(4)" ::: "memory");
    } else {
      asm volatile("s_waitcnt vmcnt(0)" ::: "memory");
    }
    __builtin_amdgcn_s_barrier();
    __builtin_amdgcn_sched_barrier(0);  // keep sV ds_reads below the barrier
    if (act) {
      __builtin_amdgcn_s_setprio(1);
#pragma unroll
      for (int nt = 0; nt < 2; nt++) {
        if (nt < ntv) {
#pragma unroll
          for (int c = 0; c < 2; c++) {
            bf16x8 pf = (nt == 0) ? (c ? pA1.v : pA0.v) : (c ? pB1.v : pB0.v);
#pragma unroll
            for (int dt = 0; dt < 4; dt++) {
              int ch2 = ((nt * 2 + c) * 2 + fq2) ^ (ql & 7);
              bf16x8 vf = *(const bf16x8*)(sV + ((dt * 32 + ql) * 8 + ch2) * 8);
              O[dt] = __builtin_amdgcn_mfma_f32_32x32x16_bf16(vf, pf, O[dt], 0, 0, 0);
            }
          }
        }
      }
      __builtin_amdgcn_s_setprio(0);
    }
  }
  float l = l_part + __shfl_xor(l_part, 32);
  if (!split) {
    float inv = 1.0f / fmaxf(l, 1e-30f);
    u16* orow = qkv + (size_t)qrow * QKV_N + h * HD;
#pragma unroll
    for (int dt = 0; dt < 4; dt++)
#pragma unroll
      for (int rg = 0; rg < 4; rg++) {
        union { u16 hh[4]; uint2 uu; } wv;
#pragma unroll
        for (int rr = 0; rr < 4; rr++) wv.hh[rr] = f2b(O[dt][rg * 4 + rr] * inv);
        *(uint2*)(orow + dt * 32 + rg * 8 + fq2 * 4) = wv.uu;
      }
  } else {
    // plain stores into this part's private region; no atomics, no memset.
    const int tile = h * 16 + (qt - 16);
    float* obase = scratch + (size_t)(part * 256 + tile) * 16384 +
                   (size_t)(wave * 32 + ql) * 128;
#pragma unroll
    for (int dt = 0; dt < 4; dt++)
#pragma unroll
      for (int rg = 0; rg < 4; rg++) {
        float4 wv = {O[dt][rg * 4 + 0], O[dt][rg * 4 + 1],
                     O[dt][rg * 4 + 2], O[dt][rg * 4 + 3]};
        *(float4*)(obase + dt * 32 + rg * 8 + fq2 * 4) = wv;
      }
    if (fq2 == 0) lbuf[(part * 256 + tile) * 128 + wave * 32 + ql] = l;
  }
}

// ---------------- combine split-tile partials ----------------
__global__ __launch_bounds__(256) void combine_split(const float* __restrict__ scratch,
                                                     const float* __restrict__ lbuf,
                                                     u16* __restrict__ qkv) {
  const int t = blockIdx.x;              // tile: h*16 + (qt-16)
  const int h = t >> 4, qt = 16 + (t & 15);
  const int tid = threadIdx.x;
  const int rsub = tid >> 4;             // 0..15
  const int d0 = (tid & 15) * 8;
  const float* s0 = scratch + (size_t)t * 16384;
  const float* s1 = scratch + (size_t)(256 + t) * 16384;
#pragma unroll
  for (int p = 0; p < 8; p++) {
    int r = p * 16 + rsub;
    float l0 = lbuf[t * 128 + r];
    float l1 = lbuf[32768 + t * 128 + r];
    float inv = 1.0f / fmaxf(l0 + l1, 1e-30f);
    const float4* a4 = (const float4*)(s0 + (size_t)r * 128 + d0);
    const float4* b4 = (const float4*)(s1 + (size_t)r * 128 + d0);
    float4 a0 = a4[0], a1 = a4[1];
    float4 b0 = b4[0], b1 = b4[1];
    union { u16 hh[8]; uint4 u; } wv;
    wv.hh[0] = f2b((a0.x + b0.x) * inv); wv.hh[1] = f2b((a0.y + b0.y) * inv);
    wv.hh[2] = f2b((a0.z + b0.z) * inv); wv.hh[3] = f2b((a0.w + b0.w) * inv);
    wv.hh[4] = f2b((a1.x + b1.x) * inv); wv.hh[5] = f2b((a1.y + b1.y) * inv);
    wv.hh[6] = f2b((a1.z + b1.z) * inv); wv.hh[7] = f2b((a1.w + b1.w) * inv);
    *(uint4*)(qkv + (size_t)(qt * 128 + r) * QKV_N + h * HD + d0) = wv.u;
  }
}

extern "C" void kernel_launch(void* const* d_in, const int* in_sizes, int n_in,
                              void* d_out, int out_size, void* d_ws, size_t ws_size,
                              hipStream_t stream) {
  const int* positions = (const int*)d_in[0];
  const float* hidden = (const float*)d_in[1];
  const float* w_qkv = (const float*)d_in[2];
  const float* w_o = (const float*)d_in[3];
  const float* qnw = (const float*)d_in[4];
  const float* knw = (const float*)d_in[5];
  float* out = (float*)d_out;

  u16* qkv  = (u16*)d_ws;                       // [4096][3072] bf16, 25.2 MB
  u16* bufA = qkv + (size_t)T_SEQ * QKV_N;      // hidden_bf16 (16.8 MB) -> w_o_bf16
  u16* bufB = bufA + (size_t)T_SEQ * HID;       // w_qkv_bf16 (12.6 MB) -> vt (4.2 MB)
  // l partials live in bufB's tail (free once gemm#1 consumed w_qkv_bf16):
  // vt occupies u16[0 .. 2097152); lbuf gets 2*128 KB after it.
  float* lbuf = (float*)(bufB + 2097152);
  // O partials for split tiles: d_out is dead until the final GEMM.
  // part0 at [0, 256*16384), part1 at [256*16384, 512*16384) — exactly out_size.
  float* scratch = out;

  // 0) one-shot f32 -> bf16 converts (lifetimes allow buffer reuse)
  conv_f32_bf16<<<4096, 256, 0, stream>>>(hidden, bufA, T_SEQ * HID / 8);
  conv_f32_bf16<<<3072, 256, 0, stream>>>(w_qkv, bufB, QKV_N * HID / 8);
  // 1) qkv = hidden @ w_qkv^T (bf16 out)
  gemm_bt<0><<<dim3(QKV_N / 128, T_SEQ / 128), 256, 0, stream>>>(
      bufA, HID, bufB, HID, qkv, QKV_N, HID);
  // 2) RoPE + RMSNorm in place (q pre-scaled by 1/sqrt(D)*log2e)
  rope_norm<<<T_SEQ, 256, 0, stream>>>(positions, qkv, qnw, knw);
  // 3) w_o convert (overwrites hidden_bf16) + v^T (overwrites w_qkv_bf16)
  conv_f32_bf16<<<2048, 256, 0, stream>>>(w_o, bufA, HID * HID / 8);
  transpose_v<<<dim3(T_SEQ / 64, NKV), 256, 0, stream>>>(qkv, bufB);
  // 4) flash attention, KV-split balanced schedule (no memset needed:
  //    every scratch/lbuf slot is written exactly once by its owner block)
  attn_kernel<<<768, 256, 0, stream>>>(qkv, bufB, scratch, lbuf);
  combine_split<<<256, 256, 0, stream>>>(scratch, lbuf, qkv);
  // 5) out = attn @ w_o^T (f32 out)
  gemm_bt<1><<<dim3(HID / 128, T_SEQ / 128), 256, 0, stream>>>(
      qkv, QKV_N, bufA, HID, out, HID, HID);
}

// Round 7
// 366.466 us; speedup vs baseline: 1.3153x; 1.1380x over previous
//
#include <hip/hip_runtime.h>
#include <hip/hip_bf16.h>

#define T_SEQ 4096
#define HID   2048
#define NH    16
#define NKV   4
#define HD    128
#define QKV_N 3072
// (1/sqrt(128)) * log2(e) folded into q at rope_norm time; attention uses exp2
#define QSCALE 0.12751744f
// static softmax max (log2 units); folded into MFMA accumulator init
#define SMAX 24.0f

typedef unsigned short u16;
typedef __bf16 bf16x8 __attribute__((ext_vector_type(8)));
typedef float floatx4 __attribute__((ext_vector_type(4)));
typedef float floatx16 __attribute__((ext_vector_type(16)));

__device__ __forceinline__ float b2f(u16 u) {
  union { unsigned int i; float f; } x; x.i = ((unsigned int)u) << 16; return x.f;
}
__device__ __forceinline__ u16 f2b(float f) {
  union { float f; unsigned int i; } x; x.f = f;
  unsigned int i = x.i;
  unsigned int r = (i + 0x7FFFu + ((i >> 16) & 1u)) >> 16;
  return (u16)r;
}
__device__ __forceinline__ void gload_lds16(const u16* g, u16* lds) {
  __builtin_amdgcn_global_load_lds(
      (const __attribute__((address_space(1))) unsigned int*)g,
      (__attribute__((address_space(3))) unsigned int*)lds, 16, 0, 0);
}

// ---------------- f32 -> bf16 bulk convert ----------------
__global__ __launch_bounds__(256) void conv_f32_bf16(const float* __restrict__ src,
                                                     u16* __restrict__ dst, int n8) {
  int i = blockIdx.x * 256 + threadIdx.x;
  if (i >= n8) return;
  const float4* s = (const float4*)(src + (size_t)i * 8);
  float4 a = s[0], b = s[1];
  union { u16 h[8]; uint4 u; } r;
  r.h[0] = f2b(a.x); r.h[1] = f2b(a.y); r.h[2] = f2b(a.z); r.h[3] = f2b(a.w);
  r.h[4] = f2b(b.x); r.h[5] = f2b(b.y); r.h[6] = f2b(b.z); r.h[7] = f2b(b.w);
  *(uint4*)(dst + (size_t)i * 8) = r.u;
}

// ---------------- bf16 GEMM: C[M,N] = A[M,K]*B[N,K]^T ----------------
// v2: BK=64, double-buffered LDS (64KB), ONE __syncthreads per K-tile.
// Stages for tile t+1 are issued at the TOP of tile t (issue-early, T14),
// so the barrier's implicit vmcnt(0) drain is ~free (loads had ~600cy of
// MFMA to land). Safety: stage-issue into buf[cur^1] happens after the
// barrier that ended all reads of that buffer (same invariant as the attn
// dbuf). T2 XOR-swizzle (byte ^= (row&7)<<4): BK=64 rows are 128B so the
// fragment read (lanes 0-15 at stride 128B) would be 8-way bank-conflicted
// linearly; swizzle spreads rows over 8 16B slots -> conflict-free.
// Staging writes LDS linearly (gload_lds requirement) with the inverse
// swizzle applied to the per-lane GLOBAL source (rule #21).
template <int CF>
__global__ __launch_bounds__(256) void gemm_bt(const u16* __restrict__ A, int lda,
                                               const u16* __restrict__ B, int ldb,
                                               void* __restrict__ Cv, int ldc, int K) {
  __shared__ __align__(16) u16 sA[2][128 * 64];
  __shared__ __align__(16) u16 sB[2][128 * 64];
  const int tid = threadIdx.x;
  const int wave = tid >> 6, lane = tid & 63;
  const int row0 = blockIdx.y * 128, col0 = blockIdx.x * 128;
  const int wm = (wave >> 1) * 64, wn = (wave & 1) * 64;
  const int frow = lane & 15;
  const int fkb = (lane >> 4) * 16;  // byte offset of k-fragment within 64B half-row

  floatx4 acc[4][4];
#pragma unroll
  for (int i = 0; i < 4; i++)
#pragma unroll
    for (int j = 0; j < 4; j++) acc[i][j] = (floatx4){0.f, 0.f, 0.f, 0.f};

  // staging: 4 passes x 16B/thread covers one 128x64 tile (16KB).
  // dest byte d = (p*256+tid)*16 (linear); row = d>>7, col byte c = d&127;
  // source col pre-swizzled: c' = c ^ ((row&7)<<4).
  const u16* gA[4];
  const u16* gB[4];
  int doff[4];  // u16 offset, wave-uniform (HW adds lane*16B)
#pragma unroll
  for (int p = 0; p < 4; p++) {
    int d = (p * 256 + tid) * 16;
    int row = d >> 7;
    int c = (d & 127) ^ ((row & 7) << 4);
    gA[p] = A + (size_t)(row0 + row) * lda + (c >> 1);
    gB[p] = B + (size_t)(col0 + row) * ldb + (c >> 1);
    doff[p] = (p * 256 + wave * 64) * 8;
  }

  // prologue: stage tile 0 into buf0
#pragma unroll
  for (int p = 0; p < 4; p++) {
    gload_lds16(gA[p], &sA[0][0] + doff[p]);
    gload_lds16(gB[p], &sB[0][0] + doff[p]);
  }
  __syncthreads();
  int cur = 0;
  for (int k0 = 0; k0 < K; k0 += 64) {
    // issue next-tile stages first (land during this tile's MFMA)
    if (k0 + 64 < K) {
      u16* san = &sA[cur ^ 1][0];
      u16* sbn = &sB[cur ^ 1][0];
#pragma unroll
      for (int p = 0; p < 4; p++) {
        gload_lds16(gA[p] + k0 + 64, san + doff[p]);
        gload_lds16(gB[p] + k0 + 64, sbn + doff[p]);
      }
    }
    const u16* pa = &sA[cur][0];
    const u16* pb = &sB[cur][0];
#pragma unroll
    for (int kk = 0; kk < 2; kk++) {
      bf16x8 af[4], bfv[4];
#pragma unroll
      for (int i = 0; i < 4; i++) {
        int rowA = wm + i * 16 + frow;
        int bA = (rowA * 128 + kk * 64 + fkb) ^ ((rowA & 7) << 4);
        af[i] = *(const bf16x8*)(pa + (bA >> 1));
        int rowB = wn + i * 16 + frow;
        int bB = (rowB * 128 + kk * 64 + fkb) ^ ((rowB & 7) << 4);
        bfv[i] = *(const bf16x8*)(pb + (bB >> 1));
      }
#pragma unroll
      for (int i = 0; i < 4; i++)
#pragma unroll
        for (int j = 0; j < 4; j++)
          acc[i][j] = __builtin_amdgcn_mfma_f32_16x16x32_bf16(af[i], bfv[j], acc[i][j], 0, 0, 0);
    }
    __syncthreads();  // own stages drained (vmcnt) + all reads of buf[cur] done
    cur ^= 1;
  }
  const int crow = (lane >> 4) * 4, ccol = lane & 15;
#pragma unroll
  for (int i = 0; i < 4; i++)
#pragma unroll
    for (int j = 0; j < 4; j++)
#pragma unroll
      for (int r = 0; r < 4; r++) {
        int rr = row0 + wm + i * 16 + crow + r;
        int cc = col0 + wn + j * 16 + ccol;
        if (CF) ((float*)Cv)[(size_t)rr * ldc + cc] = acc[i][j][r];
        else    ((u16*)Cv)[(size_t)rr * ldc + cc] = f2b(acc[i][j][r]);
      }
}

// ---------------- RoPE + RMSNorm (q scaled by QSCALE) ----------------
// fast hw sincos: angle -> revolutions -> fract -> v_sin/v_cos.
__device__ __forceinline__ void fast_sincos(float ang, float* s, float* c) {
  float r = ang * 0.15915494309189535f;
  r -= floorf(r);
  *s = __builtin_amdgcn_sinf(r);
  *c = __builtin_amdgcn_cosf(r);
}

__global__ __launch_bounds__(256) void rope_norm(const int* __restrict__ pos_arr,
                                                 u16* __restrict__ qkv,
                                                 const float* __restrict__ qnw,
                                                 const float* __restrict__ knw) {
  const int t = blockIdx.x;
  const int tid = threadIdx.x;
  const int lane = tid & 63, wave = tid >> 6;
  u16* row = qkv + (size_t)t * QKV_N;
  const float pos = (float)pos_arr[t];

  float qv[8];
  float ssq = 0.f;
#pragma unroll
  for (int i = 0; i < 8; i++) {
    int e = tid * 8 + i;
    int r = e & 127, ih = e & 63;
    float invf = exp2f(-(float)ih * 0.20762050593046015f); // log2(10000)/64
    float ang = pos * invf;
    float s, c;
    fast_sincos(ang, &s, &c);
    float val;
    if (r < 64) val = b2f(row[e]) * c - b2f(row[e + 64]) * s;
    else        val = b2f(row[e]) * c + b2f(row[e - 64]) * s;
    qv[i] = val;
    ssq += val * val;
  }
  float kv[2];
  float ssk = 0.f;
  const u16* krow = row + HID;
#pragma unroll
  for (int i = 0; i < 2; i++) {
    int e = tid * 2 + i;
    int r = e & 127, ih = e & 63;
    float invf = exp2f(-(float)ih * 0.20762050593046015f);
    float ang = pos * invf;
    float s, c;
    fast_sincos(ang, &s, &c);
    float val;
    if (r < 64) val = b2f(krow[e]) * c - b2f(krow[e + 64]) * s;
    else        val = b2f(krow[e]) * c + b2f(krow[e - 64]) * s;
    kv[i] = val;
    ssk += val * val;
  }
#pragma unroll
  for (int off = 1; off < 64; off <<= 1) {
    ssq += __shfl_xor(ssq, off);
    ssk += __shfl_xor(ssk, off);
  }
  __shared__ float rq[4], rk[4];
  if (lane == 0) { rq[wave] = ssq; rk[wave] = ssk; }
  __syncthreads();  // also orders all in-place reads before writes below
  float sq = rq[0] + rq[1] + rq[2] + rq[3];
  float sk = rk[0] + rk[1] + rk[2] + rk[3];
  float qsc = rsqrtf(sq * (1.0f / 2048.0f) + 1e-5f) * QSCALE;
  float ksc = rsqrtf(sk * (1.0f / 512.0f) + 1e-5f);
#pragma unroll
  for (int i = 0; i < 8; i++) {
    int e = tid * 8 + i;
    row[e] = f2b(qv[i] * qsc * qnw[e]);
  }
#pragma unroll
  for (int i = 0; i < 2; i++) {
    int e = tid * 2 + i;
    row[HID + e] = f2b(kv[i] * ksc * knw[e]);
  }
}

// ---------------- V transpose: vt[kvh][d][t] ----------------
__global__ __launch_bounds__(256) void transpose_v(const u16* __restrict__ qkv,
                                                   u16* __restrict__ vt) {
  __shared__ __align__(16) u16 tile[64][136];
  const int tid = threadIdx.x;
  const int h = blockIdx.y;
  const int t0 = blockIdx.x * 64;
#pragma unroll
  for (int p = 0; p < 4; p++) {
    int v = p * 256 + tid;
    int r = v >> 4, c = v & 15;
    const u16* g = qkv + (size_t)(t0 + r) * QKV_N + (HID + NKV * HD) + h * HD + c * 8;
    *(uint4*)(&tile[r][c * 8]) = *(const uint4*)g;
  }
  __syncthreads();
#pragma unroll
  for (int p = 0; p < 4; p++) {
    int v = p * 256 + tid;
    int d = v >> 3, c8 = v & 7;
    union { u16 s[8]; uint4 q; } tmp;
#pragma unroll
    for (int i = 0; i < 8; i++) tmp.s[i] = tile[c8 * 8 + i][d];
    u16* g = vt + ((size_t)h * HD + d) * T_SEQ + t0 + c8 * 8;
    *(uint4*)g = tmp.q;
  }
}

// ---------------- Flash attention v6 (measured best: 108.5 us) ----------------
// KV-split (flash-decoding) load balance: static-max softmax (fixed SMAX)
// makes partials linearly combinable (O, l just add). qt>=16 tiles split in
// two KV-halves -> every block <=32 kv-steps -> makespan ~33 steps.
// No atomics: each (tile, part) owns a disjoint f32 region in scratch
// (= d_out); plain float4 stores; combine_split sums and normalizes.
// R5/R6 lesson: direct-V (vmcnt coupling) and single-buffered V (2nd
// barrier) both regress; this dbuf K+V / one-barrier structure is the
// pipe-saturated floor for this step shape.
__device__ __forceinline__ void stage_kv(const u16* __restrict__ kbase,
                                         const u16* __restrict__ vbase, int kv0,
                                         u16* sk, u16* sv, int tid) {
  const int w = tid >> 6, lane = tid & 63;
#pragma unroll
  for (int i = 0; i < 4; i++) {
    int c = w * 256 + i * 64 + lane;
    int kv = c >> 4, ch = c & 15;
    const u16* g = kbase + (size_t)(kv0 + kv) * QKV_N + ((ch ^ (kv & 7)) * 8);
    gload_lds16(g, sk + (size_t)(w * 256 + i * 64) * 8);
  }
#pragma unroll
  for (int i = 0; i < 4; i++) {
    int c = w * 256 + i * 64 + lane;
    int d = c >> 3, c2 = c & 7;
    const u16* g = vbase + (size_t)d * T_SEQ + kv0 + ((c2 ^ (d & 7)) * 8);
    gload_lds16(g, sv + (size_t)(w * 256 + i * 64) * 8);
  }
}

__global__ __launch_bounds__(256, 2) void attn_kernel(u16* __restrict__ qkv,
                                                      const u16* __restrict__ vt,
                                                      float* __restrict__ scratch,
                                                      float* __restrict__ lbuf) {
  __shared__ __align__(16) u16 sK[2][64 * 128];  // [kv][d-chunk swizzled]
  __shared__ __align__(16) u16 sV[2][128 * 64];  // [d][kv-chunk swizzled]
  const int tid = threadIdx.x;
  const int wave = tid >> 6, lane = tid & 63;
  const int bid = blockIdx.x;

  // schedule: per-XCD (x = bid&7) list, longest-first.
  const int x = bid & 7, slot = bid >> 3;
  int h, qt, part = 0;
  bool split;
  if (slot < 80) {
    const int pr = slot / 10, r = slot - pr * 10;
    if (r < 4)      { qt = 31 - 2 * pr; part = r & 1;       h = 2 * x + (r >> 1);       split = true;  }
    else if (r < 6) { qt = 15 - pr;                         h = 2 * x + (r - 4);        split = false; }
    else            { qt = 30 - 2 * pr; part = (r - 6) & 1; h = 2 * x + ((r - 6) >> 1); split = true;  }
  } else {
    const int j = slot - 80;
    qt = 7 - (j >> 1);
    h = 2 * x + (j & 1);
    split = false;
  }
  const int s_begin = (split && part) ? (qt + 1) : 0;
  const int s_end   = split ? (part ? 2 * (qt + 1) : (qt + 1)) : 2 * (qt + 1);

  const int kvh = h >> 2;
  const int ql = lane & 31;
  const int fq2 = lane >> 5;
  const u16* kbase = qkv + HID + (size_t)kvh * HD;
  const u16* vbase = vt + (size_t)kvh * HD * T_SEQ;

  const int qw = qt * 128 + wave * 32;
  const int qmax = qw + 31;
  const int qrow = qw + ql;
  // Q B-fragments (8 k-chunks of 16 d)
  bf16x8 qf[8];
  const u16* qp = qkv + (size_t)qrow * QKV_N + h * HD + fq2 * 8;
#pragma unroll
  for (int kc = 0; kc < 8; kc++) qf[kc] = *(const bf16x8*)(qp + kc * 16);
  floatx16 O[4];
#pragma unroll
  for (int dt = 0; dt < 4; dt++)
#pragma unroll
    for (int r = 0; r < 16; r++) O[dt][r] = 0.f;
  float l_part = 0.f;

  const int nsteps = s_end - s_begin;
  stage_kv(kbase, vbase, s_begin * 64, sK[0], sV[0], tid);
#pragma unroll 1
  for (int st = 0; st < nsteps; st++) {
    const int s = s_begin + st;
    __syncthreads();  // staged buf[st&1] visible; prefetch from st-1 drained
    if (st + 1 < nsteps)
      stage_kv(kbase, vbase, (s + 1) * 64, sK[(st + 1) & 1], sV[(st + 1) & 1], tid);
    const int kv0 = s * 64;
    if (kv0 <= qmax) {
      const u16* sk = sK[st & 1];
      const u16* sv = sV[st & 1];
      const int ntv = (kv0 + 32 <= qmax) ? 2 : 1;
#pragma unroll
      for (int nt = 0; nt < 2; nt++) {
        if (nt < ntv) {
          floatx16 S;
#pragma unroll
          for (int r = 0; r < 16; r++) S[r] = -SMAX;
          __builtin_amdgcn_s_setprio(1);
#pragma unroll
          for (int kc = 0; kc < 8; kc++) {
            int ch = (kc * 2 + fq2) ^ (ql & 7);
            bf16x8 kf = *(const bf16x8*)(sk + ((nt * 32 + ql) * 16 + ch) * 8);
            S = __builtin_amdgcn_mfma_f32_32x32x16_bf16(kf, qf[kc], S, 0, 0, 0);
          }
          __builtin_amdgcn_s_setprio(0);
          const bool tmask = (kv0 + nt * 32 + 31) > qw;
#pragma unroll
          for (int r = 0; r < 16; r++) {
            float v = S[r];
            if (tmask) {
              int kvg = kv0 + nt * 32 + (r & 3) + ((r >> 2) << 3) + (fq2 << 2);
              v = (kvg > qrow) ? -1e30f : v;
            }
            float p = __builtin_amdgcn_exp2f(v);
            l_part += p;
            S[r] = p;
          }
          // In-register P (T12): pack f32 pairs to bf16 words, then
          // permlane32_swap(lo-group, hi-group) -> {j0/1 word, j4/5 word}.
          unsigned cp[8];
#pragma unroll
          for (int i = 0; i < 8; i++) {
            unsigned wv;
            asm("v_cvt_pk_bf16_f32 %0, %1, %2"
                : "=v"(wv) : "v"(S[i * 2]), "v"(S[i * 2 + 1]));
            cp[i] = wv;
          }
          union { unsigned u[4]; bf16x8 v; } pf0, pf1;
          {
            auto r0 = __builtin_amdgcn_permlane32_swap(cp[0], cp[2], false, false);
            pf0.u[0] = r0[0]; pf0.u[2] = r0[1];
            auto r1 = __builtin_amdgcn_permlane32_swap(cp[1], cp[3], false, false);
            pf0.u[1] = r1[0]; pf0.u[3] = r1[1];
            auto r2 = __builtin_amdgcn_permlane32_swap(cp[4], cp[6], false, false);
            pf1.u[0] = r2[0]; pf1.u[2] = r2[1];
            auto r3 = __builtin_amdgcn_permlane32_swap(cp[5], cp[7], false, false);
            pf1.u[1] = r3[0]; pf1.u[3] = r3[1];
          }
          __builtin_amdgcn_s_setprio(1);
#pragma unroll
          for (int c = 0; c < 2; c++) {
            bf16x8 pf = c ? pf1.v : pf0.v;
#pragma unroll
            for (int dt = 0; dt < 4; dt++) {
              int ch2 = ((nt * 2 + c) * 2 + fq2) ^ (ql & 7);
              bf16x8 vf = *(const bf16x8*)(sv + ((dt * 32 + ql) * 8 + ch2) * 8);
              O[dt] = __builtin_amdgcn_mfma_f32_32x32x16_bf16(vf, pf, O[dt], 0, 0, 0);
            }
          }
          __builtin_amdgcn_s_setprio(0);
        }
      }
    }
  }
  float l = l_part + __shfl_xor(l_part, 32);
  if (!split) {
    float inv = 1.0f / fmaxf(l, 1e-30f);
    u16* orow = qkv + (size_t)qrow * QKV_N + h * HD;
#pragma unroll
    for (int dt = 0; dt < 4; dt++)
#pragma unroll
      for (int rg = 0; rg < 4; rg++) {
        union { u16 hh[4]; uint2 uu; } wv;
#pragma unroll
        for (int rr = 0; rr < 4; rr++) wv.hh[rr] = f2b(O[dt][rg * 4 + rr] * inv);
        *(uint2*)(orow + dt * 32 + rg * 8 + fq2 * 4) = wv.uu;
      }
  } else {
    // plain stores into this part's private region; no atomics, no memset.
    const int tile = h * 16 + (qt - 16);
    float* obase = scratch + (size_t)(part * 256 + tile) * 16384 +
                   (size_t)(wave * 32 + ql) * 128;
#pragma unroll
    for (int dt = 0; dt < 4; dt++)
#pragma unroll
      for (int rg = 0; rg < 4; rg++) {
        float4 wv = {O[dt][rg * 4 + 0], O[dt][rg * 4 + 1],
                     O[dt][rg * 4 + 2], O[dt][rg * 4 + 3]};
        *(float4*)(obase + dt * 32 + rg * 8 + fq2 * 4) = wv;
      }
    if (fq2 == 0) lbuf[(part * 256 + tile) * 128 + wave * 32 + ql] = l;
  }
}

// ---------------- combine split-tile partials ----------------
__global__ __launch_bounds__(256) void combine_split(const float* __restrict__ scratch,
                                                     const float* __restrict__ lbuf,
                                                     u16* __restrict__ qkv) {
  const int t = blockIdx.x;              // tile: h*16 + (qt-16)
  const int h = t >> 4, qt = 16 + (t & 15);
  const int tid = threadIdx.x;
  const int rsub = tid >> 4;             // 0..15
  const int d0 = (tid & 15) * 8;
  const float* s0 = scratch + (size_t)t * 16384;
  const float* s1 = scratch + (size_t)(256 + t) * 16384;
#pragma unroll
  for (int p = 0; p < 8; p++) {
    int r = p * 16 + rsub;
    float l0 = lbuf[t * 128 + r];
    float l1 = lbuf[32768 + t * 128 + r];
    float inv = 1.0f / fmaxf(l0 + l1, 1e-30f);
    const float4* a4 = (const float4*)(s0 + (size_t)r * 128 + d0);
    const float4* b4 = (const float4*)(s1 + (size_t)r * 128 + d0);
    float4 a0 = a4[0], a1 = a4[1];
    float4 b0 = b4[0], b1 = b4[1];
    union { u16 hh[8]; uint4 u; } wv;
    wv.hh[0] = f2b((a0.x + b0.x) * inv); wv.hh[1] = f2b((a0.y + b0.y) * inv);
    wv.hh[2] = f2b((a0.z + b0.z) * inv); wv.hh[3] = f2b((a0.w + b0.w) * inv);
    wv.hh[4] = f2b((a1.x + b1.x) * inv); wv.hh[5] = f2b((a1.y + b1.y) * inv);
    wv.hh[6] = f2b((a1.z + b1.z) * inv); wv.hh[7] = f2b((a1.w + b1.w) * inv);
    *(uint4*)(qkv + (size_t)(qt * 128 + r) * QKV_N + h * HD + d0) = wv.u;
  }
}

extern "C" void kernel_launch(void* const* d_in, const int* in_sizes, int n_in,
                              void* d_out, int out_size, void* d_ws, size_t ws_size,
                              hipStream_t stream) {
  const int* positions = (const int*)d_in[0];
  const float* hidden = (const float*)d_in[1];
  const float* w_qkv = (const float*)d_in[2];
  const float* w_o = (const float*)d_in[3];
  const float* qnw = (const float*)d_in[4];
  const float* knw = (const float*)d_in[5];
  float* out = (float*)d_out;

  u16* qkv  = (u16*)d_ws;                       // [4096][3072] bf16, 25.2 MB
  u16* bufA = qkv + (size_t)T_SEQ * QKV_N;      // hidden_bf16 (16.8 MB) -> w_o_bf16
  u16* bufB = bufA + (size_t)T_SEQ * HID;       // w_qkv_bf16 (12.6 MB) -> vt (4.2 MB)
  // l partials live in bufB's tail (free once gemm#1 consumed w_qkv_bf16):
  // vt occupies u16[0 .. 2097152); lbuf gets 2*128 KB after it.
  float* lbuf = (float*)(bufB + 2097152);
  // O partials for split tiles: d_out is dead until the final GEMM.
  // part0 at [0, 256*16384), part1 at [256*16384, 512*16384) — exactly out_size.
  float* scratch = out;

  // 0) one-shot f32 -> bf16 converts (lifetimes allow buffer reuse)
  conv_f32_bf16<<<4096, 256, 0, stream>>>(hidden, bufA, T_SEQ * HID / 8);
  conv_f32_bf16<<<3072, 256, 0, stream>>>(w_qkv, bufB, QKV_N * HID / 8);
  // 1) qkv = hidden @ w_qkv^T (bf16 out)
  gemm_bt<0><<<dim3(QKV_N / 128, T_SEQ / 128), 256, 0, stream>>>(
      bufA, HID, bufB, HID, qkv, QKV_N, HID);
  // 2) RoPE + RMSNorm in place (q pre-scaled by 1/sqrt(D)*log2e)
  rope_norm<<<T_SEQ, 256, 0, stream>>>(positions, qkv, qnw, knw);
  // 3) w_o convert (overwrites hidden_bf16) + v^T (overwrites w_qkv_bf16)
  conv_f32_bf16<<<2048, 256, 0, stream>>>(w_o, bufA, HID * HID / 8);
  transpose_v<<<dim3(T_SEQ / 64, NKV), 256, 0, stream>>>(qkv, bufB);
  // 4) flash attention, KV-split balanced schedule (no memset needed:
  //    every scratch/lbuf slot is written exactly once by its owner block)
  attn_kernel<<<768, 256, 0, stream>>>(qkv, bufB, scratch, lbuf);
  combine_split<<<256, 256, 0, stream>>>(scratch, lbuf, qkv);
  // 5) out = attn @ w_o^T (f32 out)
  gemm_bt<1><<<dim3(HID / 128, T_SEQ / 128), 256, 0, stream>>>(
      qkv, QKV_N, bufA, HID, out, HID, HID);
}